// Round 5
// baseline (453.780 us; speedup 1.0000x reference)
//
#include <hip/hip_runtime.h>
#include <hip/hip_bf16.h>
#include <cmath>

// ---------------- problem constants ----------------
constexpr int Nn  = 50000;
constexpr int Np  = 50176;       // Nn padded to 256
constexpr int Ee  = 800000;
constexpr int ET  = Ee + Nn;     // edges + self loops
constexpr int F   = 256;         // H*C
constexpr int DO  = 32;

// f32 weight block offsets
constexpr int A1S=4096, A1D=4352, B1O=4608,
              A2S=4864, A2D=5120, B2O=5376,
              A3S=5632, A3D=5664, B3O=5696,
              G1O=5728, BE1O=5984, G2O=6240, BE2O=6496,
              WR1O=6752, BR1O=7776, WR2O=7808, BR2O=8000, WTOT=8006;

struct InPtrs { const void* p[22]; };

typedef __attribute__((ext_vector_type(8))) short short8v;
typedef __attribute__((ext_vector_type(8))) unsigned short ushort8v;
typedef __attribute__((ext_vector_type(4))) float f32x4;

__device__ __forceinline__ float ld_in(const void* p, int i, int bf){
  if (bf){ unsigned u = (unsigned)((const unsigned short*)p)[i];
           union{unsigned u; float f;} c; c.u = u<<16; return c.f; }
  return ((const float*)p)[i];
}
__device__ __forceinline__ float b2f(unsigned short u){
  union{unsigned u; float f;} c; c.u = ((unsigned)u)<<16; return c.f;
}
__device__ __forceinline__ unsigned short f2b(float f){
  union{float f; unsigned u;} c; c.f=f; unsigned u=c.u;
  return (unsigned short)((u + 0x7fffu + ((u>>16)&1u))>>16);
}
__device__ __forceinline__ void st_out(void* o, int bf, long i, float v){
  if (bf) ((unsigned short*)o)[i] = f2b(v);
  else ((float*)o)[i]=v;
}
__device__ __forceinline__ float wsum64(float v){
  #pragma unroll
  for (int o=32;o;o>>=1) v += __shfl_xor(v,o);
  return v;
}

// ---------------- dtype detect ----------------
__global__ void k_detect(const unsigned* __restrict__ xr, int* __restrict__ flag){
  __shared__ int cnt;
  if (threadIdx.x==0) cnt=0;
  __syncthreads();
  int bad=0;
  for (int i=threadIdx.x;i<2048;i+=256){
    unsigned lo = xr[i]&0xffffu;
    unsigned ex = (lo>>7)&0xffu;
    if (ex>=133u) bad++;
  }
  atomicAdd(&cnt,bad);
  __syncthreads();
  if (threadIdx.x==0) *flag = (cnt<8) ? 1 : 0;   // 1 = inputs are bf16
}

// ---------------- merged prep: xpad + W2T + W1T + W3T + small weights ----------------
__global__ void k_prep(InPtrs ip, float* __restrict__ wf,
                       unsigned short* __restrict__ xp,
                       unsigned short* __restrict__ w1t,
                       unsigned short* __restrict__ w2t,
                       unsigned short* __restrict__ w3t,
                       const int* __restrict__ flagp){
  int g = blockIdx.x*256 + threadIdx.x;
  int bf = *flagp;
  if (g < Np*32){
    int row=g>>5, k=g&31;
    float v = (row<Nn && k<16)? ld_in(ip.p[0], row*16+k, bf) : 0.f;
    xp[g]=f2b(v); return;
  }
  g -= Np*32;
  if (g < 256*256){
    int n=g>>8, k=g&255;
    w2t[n*256+k] = f2b(ld_in(ip.p[6], k*256+n, bf)); return;
  }
  g -= 256*256;
  if (g < 256*32){
    int n=g>>5, k=g&31;
    w1t[g] = (k<16)? f2b(ld_in(ip.p[2], k*256+n, bf)) : (unsigned short)0; return;
  }
  g -= 256*32;
  if (g < 32*256){
    int n=g>>8, k=g&255;
    w3t[n*256+k] = f2b(ld_in(ip.p[10], k*32+n, bf)); return;
  }
  g -= 32*256;
  const int SIX[17]={3,4,5,7,8,9,11,12,13,14,15,16,17,18,19,20,21};
  const int SOF[17]={A1S,A1D,B1O,A2S,A2D,B2O,A3S,A3D,B3O,
                     G1O,BE1O,G2O,BE2O,WR1O,BR1O,WR2O,BR2O};
  const int SSZ[17]={256,256,256,256,256,256,32,32,32,
                     256,256,256,256,1024,32,192,6};
  for (int j=0;j<17;j++){
    if (g < SSZ[j]){ wf[SOF[j]+g] = ld_in(ip.p[SIX[j]], g, bf); return; }
    g -= SSZ[j];
  }
}

// ---------------- CSR build ----------------
__global__ void k_count(const int* __restrict__ ei, int* __restrict__ deg){
  int g = blockIdx.x*256 + threadIdx.x;
  if (g < Ee) atomicAdd(&deg[ei[Ee+g]], 1);
}
__global__ void __launch_bounds__(256) k_scan_blk(const int* __restrict__ deg,
                                                  int* __restrict__ offtmp,
                                                  int* __restrict__ bsum){
  __shared__ int s[256];
  int t = threadIdx.x, i = blockIdx.x*256 + t;
  int v = (i<Nn) ? deg[i]+1 : 0;
  s[t]=v; __syncthreads();
  #pragma unroll
  for (int d=1; d<256; d<<=1){
    int x = (t>=d)? s[t-d] : 0; __syncthreads();
    s[t]+=x; __syncthreads();
  }
  if (i<Nn) offtmp[i] = s[t]-v;
  if (t==255) bsum[blockIdx.x] = s[255];
}
__global__ void __launch_bounds__(256) k_scan_top(const int* __restrict__ bsum,
                                                  int* __restrict__ bpre,
                                                  int* __restrict__ off){
  __shared__ int s[256];
  int t=threadIdx.x;
  int v = (t<196)? bsum[t]:0;
  s[t]=v; __syncthreads();
  #pragma unroll
  for (int d=1;d<256;d<<=1){ int x=(t>=d)?s[t-d]:0; __syncthreads(); s[t]+=x; __syncthreads(); }
  if (t<196) bpre[t]=s[t]-v;
  if (t==0) off[Nn]=ET;
}
__global__ void __launch_bounds__(256) k_scan_add(const int* __restrict__ offtmp,
                                                  const int* __restrict__ bpre,
                                                  int* __restrict__ off,
                                                  int* __restrict__ cursor){
  int i = blockIdx.x*256 + threadIdx.x;
  if (i<Nn){ int st = offtmp[i]+bpre[i>>8]; off[i]=st; cursor[i]=st; }
}
__global__ void k_fill(const int* __restrict__ ei, int* __restrict__ cursor,
                       int* __restrict__ csr, int* __restrict__ edst){
  int g = blockIdx.x*256 + threadIdx.x;
  if (g < Ee){
    int s = ei[g], d = ei[Ee+g];
    int p = atomicAdd(&cursor[d],1);
    csr[p] = s; edst[p] = d;
  } else if (g < ET){
    int n = g - Ee;
    int p = atomicAdd(&cursor[n],1);
    csr[p] = n; edst[p] = n;
  }
}

// ---------------- MFMA GEMM + fused score epilogue ----------------
// EPI=0: none. EPI=1: as/ad per 4 heads (needs BN=256, WAVES_N=2).
// EPI=2: s3/d3 single head over 32 cols (BN=32, WAVES_N=1).
template<int BM,int BN,int WAVES_M,int WAVES_N,int KT,int EPI>
__global__ void __launch_bounds__(256) k_gemm_mfma(const unsigned short* __restrict__ Ag,
                                                   const unsigned short* __restrict__ BTg,
                                                   unsigned short* __restrict__ Cg,
                                                   const float* __restrict__ aswp,
                                                   const float* __restrict__ adwp,
                                                   float* __restrict__ aso,
                                                   float* __restrict__ ado,
                                                   int M, int N, int nMB){
  constexpr int WMT = BM/(WAVES_M*16);
  constexpr int WNT = BN/(WAVES_N*16);
  __shared__ unsigned short As[4*BM*8];
  __shared__ unsigned short Bs[4*BN*8];
  int bm = blockIdx.x % nMB, bn = blockIdx.x / nMB;
  int row0 = bm*BM, col0 = bn*BN;
  int tid = threadIdx.x, lane = tid&63, wid = tid>>6;
  int wm = wid % WAVES_M, wn = wid / WAVES_M;
  f32x4 acc[WMT][WNT];
  #pragma unroll
  for (int m=0;m<WMT;m++)
    #pragma unroll
    for (int n=0;n<WNT;n++){ acc[m][n].x=0.f; acc[m][n].y=0.f; acc[m][n].z=0.f; acc[m][n].w=0.f; }

  int cl = lane>>4, rl = lane&15;
  for (int kk=0; kk<KT; kk+=32){
    __syncthreads();
    for (int idx=tid; idx<4*BM; idx+=256){
      int r = idx>>2, c = idx&3;
      short8v v = *(const short8v*)(Ag + (size_t)(row0+r)*KT + kk + c*8);
      *(short8v*)(As + (c*BM + (r ^ (c<<2)))*8) = v;
    }
    for (int idx=tid; idx<4*BN; idx+=256){
      int r = idx>>2, c = idx&3;
      short8v v = *(const short8v*)(BTg + (size_t)(col0+r)*KT + kk + c*8);
      *(short8v*)(Bs + (c*BN + (r ^ (c<<2)))*8) = v;
    }
    __syncthreads();
    short8v af[WMT], bfv[WNT];
    #pragma unroll
    for (int m=0;m<WMT;m++){
      int r = wm*WMT*16 + m*16 + rl;
      af[m] = *(const short8v*)(As + (cl*BM + (r ^ (cl<<2)))*8);
    }
    #pragma unroll
    for (int n=0;n<WNT;n++){
      int r = wn*WNT*16 + n*16 + rl;
      bfv[n] = *(const short8v*)(Bs + (cl*BN + (r ^ (cl<<2)))*8);
    }
    #pragma unroll
    for (int m=0;m<WMT;m++)
      #pragma unroll
      for (int n=0;n<WNT;n++)
        acc[m][n] = __builtin_amdgcn_mfma_f32_16x16x32_bf16(af[m], bfv[n], acc[m][n], 0,0,0);
  }
  #pragma unroll
  for (int m=0;m<WMT;m++){
    int rbase = row0 + wm*WMT*16 + m*16 + (lane>>4)*4;
    #pragma unroll
    for (int n=0;n<WNT;n++){
      int col = col0 + wn*WNT*16 + n*16 + (lane&15);
      #pragma unroll
      for (int q=0;q<4;q++){
        int row = rbase + q;
        if (row < M) Cg[(size_t)row*N + col] = f2b(acc[m][n][q]);
      }
    }
  }
  if constexpr (EPI==1){
    // wave wn owns heads 2wn, 2wn+1 for its rows (BN=256, WAVES_N=2)
    #pragma unroll
    for (int m=0;m<WMT;m++){
      #pragma unroll
      for (int q=0;q<4;q++){
        float ps0=0,pd0=0,ps1=0,pd1=0;
        #pragma unroll
        for (int n=0;n<WNT;n++){
          int col = wn*(WNT*16) + n*16 + (lane&15);
          float av = acc[m][n][q];
          float ws = aswp[col], wd = adwp[col];
          if (n < WNT/2){ ps0 += av*ws; pd0 += av*wd; }
          else          { ps1 += av*ws; pd1 += av*wd; }
        }
        #pragma unroll
        for (int o=1;o<16;o<<=1){
          ps0 += __shfl_xor(ps0,o); pd0 += __shfl_xor(pd0,o);
          ps1 += __shfl_xor(ps1,o); pd1 += __shfl_xor(pd1,o);
        }
        int row = row0 + wm*(WMT*16) + m*16 + (lane>>4)*4 + q;
        if ((lane&15)==0 && row<M){
          int h0 = wn*2;
          aso[(size_t)row*4+h0  ]=ps0; aso[(size_t)row*4+h0+1]=ps1;
          ado[(size_t)row*4+h0  ]=pd0; ado[(size_t)row*4+h0+1]=pd1;
        }
      }
    }
  } else if constexpr (EPI==2){
    #pragma unroll
    for (int m=0;m<WMT;m++){
      #pragma unroll
      for (int q=0;q<4;q++){
        float ps=0,pd=0;
        #pragma unroll
        for (int n=0;n<WNT;n++){
          int col = n*16 + (lane&15);
          float av = acc[m][n][q];
          ps += av*aswp[col]; pd += av*adwp[col];
        }
        #pragma unroll
        for (int o=1;o<16;o<<=1){ ps+=__shfl_xor(ps,o); pd+=__shfl_xor(pd,o); }
        int row = row0 + wm*(WMT*16) + m*16 + (lane>>4)*4 + q;
        if ((lane&15)==0 && row<M){ aso[row]=ps; ado[row]=pd; }
      }
    }
  }
}

// ---------------- per-edge unnormalized weights (4 heads) ----------------
__global__ void __launch_bounds__(256) k_wexp(const float* __restrict__ as4,
                                              const float* __restrict__ ad4,
                                              const int* __restrict__ csr,
                                              const int* __restrict__ edst,
                                              float* __restrict__ wE){
  int e = blockIdx.x*256 + threadIdx.x;
  if (e>=ET) return;
  int s=csr[e], d=edst[e];
  const float4 a = *reinterpret_cast<const float4*>(as4 + (size_t)s*4);
  const float4 b = *reinterpret_cast<const float4*>(ad4 + (size_t)d*4);
  float t0=a.x+b.x; t0=t0>0.f?t0:0.2f*t0;
  float t1=a.y+b.y; t1=t1>0.f?t1:0.2f*t1;
  float t2=a.z+b.z; t2=t2>0.f?t2:0.2f*t2;
  float t3=a.w+b.w; t3=t3>0.f?t3:0.2f*t3;
  float4 w; w.x=__expf(t0); w.y=__expf(t1); w.z=__expf(t2); w.w=__expf(t3);
  *reinterpret_cast<float4*>(wE + (size_t)e*4) = w;
}

// ---------------- per-edge weights layer 3 (1 head) ----------------
__global__ void __launch_bounds__(256) k_wexp3(const float* __restrict__ s3,
                                               const float* __restrict__ d3,
                                               const int* __restrict__ csr,
                                               const int* __restrict__ edst,
                                               float* __restrict__ w3e){
  int e = blockIdx.x*256 + threadIdx.x;
  if (e>=ET) return;
  float t = s3[csr[e]] + d3[edst[e]];
  t = t>0.f? t : 0.2f*t;
  w3e[e] = __expf(t);
}

// ---------------- GAT aggregation + bias + LN + ELU (layers 1,2) ----------------
__global__ void __launch_bounds__(256) k_agg(const unsigned short* __restrict__ Hs,
                                             const float* __restrict__ wE,
                                             const float* __restrict__ bias,
                                             const float* __restrict__ gam,
                                             const float* __restrict__ bet,
                                             const int* __restrict__ off,
                                             const int* __restrict__ csr,
                                             unsigned short* __restrict__ out){
  int wid = threadIdx.x>>6, lane = threadIdx.x&63;
  int n = blockIdx.x*4 + wid;
  if (n>=Nn) return;
  int half = lane>>5, c8 = lane&31;       // channels c8*8 .. c8*8+7
  int h = c8>>3;
  const unsigned short* hbase = Hs + c8*8;
  int o0=off[n], o1=off[n+1], cnt=o1-o0;
  int mid = o0 + (cnt>>1);
  int lo = half? mid : o0;
  int hi = half? o1  : mid;
  float a0=0,a1=0,a2=0,a3=0,a4=0,a5=0,a6=0,a7=0,den=0;
  int e = lo;
  for (; e+3<hi; e+=4){
    int s0=csr[e], s1=csr[e+1], s2=csr[e+2], s3v=csr[e+3];
    float w0=wE[e*4+h], w1=wE[(e+1)*4+h], w2=wE[(e+2)*4+h], w3=wE[(e+3)*4+h];
    const ushort8v hv0 = *reinterpret_cast<const ushort8v*>(hbase + (size_t)s0*F);
    const ushort8v hv1 = *reinterpret_cast<const ushort8v*>(hbase + (size_t)s1*F);
    const ushort8v hv2 = *reinterpret_cast<const ushort8v*>(hbase + (size_t)s2*F);
    const ushort8v hv3 = *reinterpret_cast<const ushort8v*>(hbase + (size_t)s3v*F);
    den += (w0+w1)+(w2+w3);
    a0 += w0*b2f(hv0[0]) + w1*b2f(hv1[0]) + w2*b2f(hv2[0]) + w3*b2f(hv3[0]);
    a1 += w0*b2f(hv0[1]) + w1*b2f(hv1[1]) + w2*b2f(hv2[1]) + w3*b2f(hv3[1]);
    a2 += w0*b2f(hv0[2]) + w1*b2f(hv1[2]) + w2*b2f(hv2[2]) + w3*b2f(hv3[2]);
    a3 += w0*b2f(hv0[3]) + w1*b2f(hv1[3]) + w2*b2f(hv2[3]) + w3*b2f(hv3[3]);
    a4 += w0*b2f(hv0[4]) + w1*b2f(hv1[4]) + w2*b2f(hv2[4]) + w3*b2f(hv3[4]);
    a5 += w0*b2f(hv0[5]) + w1*b2f(hv1[5]) + w2*b2f(hv2[5]) + w3*b2f(hv3[5]);
    a6 += w0*b2f(hv0[6]) + w1*b2f(hv1[6]) + w2*b2f(hv2[6]) + w3*b2f(hv3[6]);
    a7 += w0*b2f(hv0[7]) + w1*b2f(hv1[7]) + w2*b2f(hv2[7]) + w3*b2f(hv3[7]);
  }
  for (; e<hi; ++e){
    int sv=csr[e];
    float w=wE[e*4+h];
    const ushort8v hv = *reinterpret_cast<const ushort8v*>(hbase + (size_t)sv*F);
    den += w;
    a0 += w*b2f(hv[0]); a1 += w*b2f(hv[1]); a2 += w*b2f(hv[2]); a3 += w*b2f(hv[3]);
    a4 += w*b2f(hv[4]); a5 += w*b2f(hv[5]); a6 += w*b2f(hv[6]); a7 += w*b2f(hv[7]);
  }
  // combine half-waves
  a0 += __shfl_xor(a0,32); a1 += __shfl_xor(a1,32);
  a2 += __shfl_xor(a2,32); a3 += __shfl_xor(a3,32);
  a4 += __shfl_xor(a4,32); a5 += __shfl_xor(a5,32);
  a6 += __shfl_xor(a6,32); a7 += __shfl_xor(a7,32);
  den += __shfl_xor(den,32);
  float rs = 1.f/(den + 1e-16f);
  int c = c8*8;
  const float4 bv0 = *reinterpret_cast<const float4*>(bias + c);
  const float4 bv1 = *reinterpret_cast<const float4*>(bias + c + 4);
  a0=a0*rs+bv0.x; a1=a1*rs+bv0.y; a2=a2*rs+bv0.z; a3=a3*rs+bv0.w;
  a4=a4*rs+bv1.x; a5=a5*rs+bv1.y; a6=a6*rs+bv1.z; a7=a7*rs+bv1.w;
  // LayerNorm over 256 (values duplicated across halves -> /512)
  float sl = a0+a1+a2+a3+a4+a5+a6+a7;
  float mu = wsum64(sl)*(1.f/512.f);
  float d0=a0-mu,d1=a1-mu,d2=a2-mu,d3=a3-mu,d4=a4-mu,d5=a5-mu,d6=a6-mu,d7=a7-mu;
  float ql = d0*d0+d1*d1+d2*d2+d3*d3+d4*d4+d5*d5+d6*d6+d7*d7;
  float var = wsum64(ql)*(1.f/512.f);
  float r = rsqrtf(var + 1e-5f);
  const float4 gv0 = *reinterpret_cast<const float4*>(gam + c);
  const float4 gv1 = *reinterpret_cast<const float4*>(gam + c + 4);
  const float4 ev0 = *reinterpret_cast<const float4*>(bet + c);
  const float4 ev1 = *reinterpret_cast<const float4*>(bet + c + 4);
  float y0=d0*r*gv0.x+ev0.x, y1=d1*r*gv0.y+ev0.y, y2=d2*r*gv0.z+ev0.z, y3=d3*r*gv0.w+ev0.w;
  float y4=d4*r*gv1.x+ev1.x, y5=d5*r*gv1.y+ev1.y, y6=d6*r*gv1.z+ev1.z, y7=d7*r*gv1.w+ev1.w;
  y0=y0>0.f?y0:expm1f(y0); y1=y1>0.f?y1:expm1f(y1);
  y2=y2>0.f?y2:expm1f(y2); y3=y3>0.f?y3:expm1f(y3);
  y4=y4>0.f?y4:expm1f(y4); y5=y5>0.f?y5:expm1f(y5);
  y6=y6>0.f?y6:expm1f(y6); y7=y7>0.f?y7:expm1f(y7);
  if (half==0){
    ushort8v ov;
    ov[0]=f2b(y0); ov[1]=f2b(y1); ov[2]=f2b(y2); ov[3]=f2b(y3);
    ov[4]=f2b(y4); ov[5]=f2b(y5); ov[6]=f2b(y6); ov[7]=f2b(y7);
    *reinterpret_cast<ushort8v*>(out + (size_t)n*F + c) = ov;
  }
}

// ---------------- layer 3 aggregation + bias + fused risk head ----------------
__global__ void __launch_bounds__(256) k_agg3r(const unsigned short* __restrict__ C3,
                                               const float* __restrict__ w3e,
                                               const float* __restrict__ wf,
                                               const int* __restrict__ off,
                                               const int* __restrict__ csr,
                                               void* __restrict__ dout,
                                               const int* __restrict__ flagp){
  int wid=threadIdx.x>>6, lane=threadIdx.x&63;
  int n = blockIdx.x*4 + wid;
  if (n>=Nn) return;
  int bf = *flagp;
  int g = lane>>3, j = lane&7;            // 8 groups x 8 lanes; channels j*4..j*4+3
  int o0=off[n], o1=off[n+1], cnt=o1-o0;
  int lo = o0 + ((cnt*g)>>3), hi = o0 + ((cnt*(g+1))>>3);
  float a0=0,a1=0,a2=0,a3=0,den=0;
  for (int e=lo; e<hi; ++e){
    int s=csr[e];
    float w=w3e[e];
    const ushort4 hv = *reinterpret_cast<const ushort4*>(C3 + (size_t)s*DO + j*4);
    den += w;
    a0 += w*b2f(hv.x); a1 += w*b2f(hv.y); a2 += w*b2f(hv.z); a3 += w*b2f(hv.w);
  }
  #pragma unroll
  for (int o=8;o<64;o<<=1){
    a0 += __shfl_xor(a0,o); a1 += __shfl_xor(a1,o);
    a2 += __shfl_xor(a2,o); a3 += __shfl_xor(a3,o);
    den += __shfl_xor(den,o);
  }
  float rs = 1.f/(den + 1e-16f);
  const float4 bv = *reinterpret_cast<const float4*>(wf + B3O + j*4);
  float v0=a0*rs+bv.x, v1=a1*rs+bv.y, v2=a2*rs+bv.z, v3=a3*rs+bv.w;
  if (lane<8){
    long bo = (long)n*DO + lane*4;
    st_out(dout,bf,bo  ,v0); st_out(dout,bf,bo+1,v1);
    st_out(dout,bf,bo+2,v2); st_out(dout,bf,bo+3,v3);
  }
  // materialize full 32-vector on every lane
  float hk[32];
  #pragma unroll
  for (int k=0;k<32;k++){
    float src = ((k&3)==0)? v0 : ((k&3)==1)? v1 : ((k&3)==2)? v2 : v3;
    hk[k] = __shfl(src, k>>2);
  }
  // hidden layer: lane j' (<32) computes t1[j']
  float t1 = 0.f;
  if (lane<32){
    t1 = wf[BR1O+lane];
    #pragma unroll
    for (int k=0;k<32;k++) t1 += hk[k]*wf[WR1O + k*32 + lane];
    t1 = fmaxf(t1, 0.f);
  }
  // output layer: 6 reductions over 32 lanes
  float p0=0,p1=0,p2=0,p3=0,p4=0,p5=0;
  if (lane<32){
    const float* w2r = wf + WR2O + lane*6;
    p0=t1*w2r[0]; p1=t1*w2r[1]; p2=t1*w2r[2];
    p3=t1*w2r[3]; p4=t1*w2r[4]; p5=t1*w2r[5];
  }
  #pragma unroll
  for (int m=1;m<64;m<<=1){
    p0+=__shfl_xor(p0,m); p1+=__shfl_xor(p1,m); p2+=__shfl_xor(p2,m);
    p3+=__shfl_xor(p3,m); p4+=__shfl_xor(p4,m); p5+=__shfl_xor(p5,m);
  }
  if (lane<6){
    float s = (lane==0)?p0:(lane==1)?p1:(lane==2)?p2:(lane==3)?p3:(lane==4)?p4:p5;
    s += wf[BR2O+lane];
    float r = 1.f/(1.f+__expf(-s));
    st_out(dout, bf, (long)Nn*32 + (long)n*6 + lane, r);
  }
}

// ---------------- launcher ----------------
extern "C" void kernel_launch(void* const* d_in, const int* in_sizes, int n_in,
                              void* d_out, int out_size, void* d_ws, size_t ws_size,
                              hipStream_t stream){
  char* base = (char*)d_ws;
  size_t cur = 0;
  auto alloc = [&](size_t bytes)->char*{
    cur = (cur + 255) & ~(size_t)255;
    char* r = base + cur; cur += bytes; return r;
  };
  int*   flag = (int*)  alloc(4);
  float* wf   = (float*)alloc(sizeof(float)*WTOT);
  unsigned short* xpad = (unsigned short*)alloc(sizeof(short)*(size_t)Np*32);
  unsigned short* w1t = (unsigned short*)alloc(sizeof(short)*256*32);
  unsigned short* w2t = (unsigned short*)alloc(sizeof(short)*256*256);
  unsigned short* w3t = (unsigned short*)alloc(sizeof(short)*32*256);
  int*   deg  = (int*)  alloc(sizeof(int)*Nn);
  int*   offt = (int*)  alloc(sizeof(int)*Nn);
  int*   bsum = (int*)  alloc(sizeof(int)*256);
  int*   bpre = (int*)  alloc(sizeof(int)*256);
  int*   off  = (int*)  alloc(sizeof(int)*(Nn+1));
  int*   curs = (int*)  alloc(sizeof(int)*Nn);
  int*   csr  = (int*)  alloc(sizeof(int)*ET);
  int*   edst = (int*)  alloc(sizeof(int)*ET);
  unsigned short* G  = (unsigned short*)alloc(sizeof(short)*(size_t)Np*F);
  unsigned short* Hb = (unsigned short*)alloc(sizeof(short)*(size_t)Np*F);
  unsigned short* C3 = (unsigned short*)alloc(sizeof(short)*(size_t)Np*DO);
  float* as4  = (float*)alloc(sizeof(float)*(size_t)Nn*4);
  float* ad4  = (float*)alloc(sizeof(float)*(size_t)Nn*4);
  float* wE   = (float*)alloc(sizeof(float)*(size_t)ET*4);
  float* s3   = (float*)alloc(sizeof(float)*Nn);
  float* d3   = (float*)alloc(sizeof(float)*Nn);
  float* w3e  = (float*)alloc(sizeof(float)*(size_t)ET);

  const int* ei = (const int*)d_in[1];
  InPtrs ip;
  for (int i=0;i<22;i++) ip.p[i]=d_in[i];

  k_detect<<<1,256,0,stream>>>((const unsigned*)d_in[0], flag);
  {
    int total = Np*32 + 256*256 + 256*32 + 32*256 + 3910;
    k_prep<<<(total+255)/256,256,0,stream>>>(ip, wf, xpad, w1t, w2t, w3t, flag);
  }
  (void)hipMemsetAsync(deg, 0, sizeof(int)*Nn, stream);
  k_count<<<(Ee+255)/256,256,0,stream>>>(ei, deg);
  k_scan_blk<<<196,256,0,stream>>>(deg, offt, bsum);
  k_scan_top<<<1,256,0,stream>>>(bsum, bpre, off);
  k_scan_add<<<196,256,0,stream>>>(offt, bpre, off, curs);
  k_fill<<<(ET+255)/256,256,0,stream>>>(ei, curs, csr, edst);

  dim3 wg((Nn+3)/4);
  constexpr int nMB = Np/64;            // 784
  dim3 eg((ET+255)/256);
  // layer 1 (MFMA K=32 zero-padded, fused as/ad epilogue)
  k_gemm_mfma<64,256,2,2,32,1><<<nMB,256,0,stream>>>(xpad, w1t, G,
      wf+A1S, wf+A1D, as4, ad4, Nn, 256, nMB);
  k_wexp<<<eg,256,0,stream>>>(as4, ad4, csr, edst, wE);
  k_agg <<<wg,256,0,stream>>>(G, wE, wf+B1O, wf+G1O, wf+BE1O, off, csr, Hb);
  // layer 2
  k_gemm_mfma<64,256,2,2,256,1><<<nMB,256,0,stream>>>(Hb, w2t, G,
      wf+A2S, wf+A2D, as4, ad4, Nn, 256, nMB);
  k_wexp<<<eg,256,0,stream>>>(as4, ad4, csr, edst, wE);
  k_agg <<<wg,256,0,stream>>>(G, wE, wf+B2O, wf+G2O, wf+BE2O, off, csr, Hb);
  // layer 3 (fused s3/d3 epilogue)
  k_gemm_mfma<64,32,4,1,256,2><<<nMB,256,0,stream>>>(Hb, w3t, C3,
      wf+A3S, wf+A3D, s3, d3, Nn, 32, nMB);
  k_wexp3<<<eg,256,0,stream>>>(s3, d3, csr, edst, w3e);
  k_agg3r<<<wg,256,0,stream>>>(C3, w3e, wf, off, csr, d_out, flag);
}